// Round 15
// baseline (493.632 us; speedup 1.0000x reference)
//
#include <hip/hip_runtime.h>

typedef __attribute__((ext_vector_type(8))) short bf16x8;
typedef __attribute__((ext_vector_type(4))) short s16x4;
typedef __attribute__((ext_vector_type(4))) float f32x4;

__device__ __forceinline__ float bf2f(unsigned short u) {
    union { unsigned int u; float f; } x; x.u = ((unsigned int)u) << 16; return x.f;
}
__device__ __forceinline__ unsigned short f2bf(float f) {
    union { float f; unsigned int u; } x; x.f = f;
    unsigned int u = x.u;
    unsigned int r = (u + 0x7fffu + ((u >> 16) & 1u)) >> 16;
    return (unsigned short)r;
}

#define GLDS16(gp, lp)                                                        \
    __builtin_amdgcn_global_load_lds(                                         \
        (const __attribute__((address_space(1))) void*)(gp),                  \
        (__attribute__((address_space(3))) void*)(lp), 16, 0, 0)

// ---------------------------------------------------------------------------
// GEMM body: C[M, N=1024] = A[M,K=1024] @ W^T + bias. A,W bf16 (W=[N,K]).
// 256x256 tile, BK=64, 8 waves, 128KB LDS dbuf, depth-2 prefetch, counted
// vmcnt(8), raw s_barrier, setprio, XOR-swizzled staging (verified conflicts=0).
// OUT_MODE: 0 = bf16 [row][col], 1 = f32 [row][col], 2 = bf16 transposed
//           [b][col][t] (row = b*2048+t).
// ---------------------------------------------------------------------------
template<int OUT_MODE>
__device__ __forceinline__
void gemm_body(const unsigned short* __restrict__ A, const unsigned short* __restrict__ Bw,
               const float* __restrict__ bias, void* __restrict__ out_,
               int bid, int nb, unsigned short* sAp, unsigned short* sBp) {
    const int tid  = threadIdx.x;
    const int lane = tid & 63;
    const int w    = tid >> 6;
    const int wr   = w >> 2, wc = w & 3;
    const int fr   = lane & 15, g4 = lane >> 4;

    const int qq  = nb >> 3;
    const int swz = qq ? (bid & 7) * qq + (bid >> 3) : bid;
    const int  col0 = (swz & 3) * 256;
    const long row0 = (long)(swz >> 2) * 256;

    const int srow = tid >> 3;
    const int sj   = (tid & 7) ^ (srow & 7);
    const unsigned short* gA = A  + (size_t)(row0 + srow) * 1024 + sj * 8;
    const unsigned short* gB = Bw + (size_t)(col0 + srow) * 1024 + sj * 8;
    const int ldst = w * 1024;

    auto stage = [&](int buf, int t) {
        const unsigned short* a = gA + t * 64;
        const unsigned short* b = gB + t * 64;
        char* dA = (char*)(sAp + buf * 16384);
        char* dB = (char*)(sBp + buf * 16384);
#pragma unroll
        for (int r = 0; r < 4; ++r)
            GLDS16(a + r * 65536, (__attribute__((address_space(3))) char*)(dA + r * 8192 + ldst));
#pragma unroll
        for (int r = 0; r < 4; ++r)
            GLDS16(b + r * 65536, (__attribute__((address_space(3))) char*)(dB + r * 8192 + ldst));
    };

    f32x4 acc[8][4];
#pragma unroll
    for (int m = 0; m < 8; ++m)
#pragma unroll
        for (int n = 0; n < 4; ++n) acc[m][n] = (f32x4){0.f, 0.f, 0.f, 0.f};

    stage(0, 0);
    stage(1, 1);

    const int mskK = (fr & 7) << 4;

    for (int t = 0; t < 16; ++t) {
        if (t < 15) asm volatile("s_waitcnt vmcnt(8)" ::: "memory");
        else        asm volatile("s_waitcnt vmcnt(0)" ::: "memory");
        asm volatile("s_barrier" ::: "memory");
        __builtin_amdgcn_sched_barrier(0);

        const char* la = (const char*)(sAp + (t & 1) * 16384);
        const char* lb = (const char*)(sBp + (t & 1) * 16384);

        bf16x8 bF[2][4];
#pragma unroll
        for (int c = 0; c < 2; ++c)
#pragma unroll
            for (int n = 0; n < 4; ++n) {
                const int row = wc * 64 + n * 16 + fr;
                bF[c][n] = *(const bf16x8*)(lb + row * 128 + ((c * 64 + g4 * 16) ^ mskK));
            }
#pragma unroll
        for (int mh = 0; mh < 2; ++mh) {
            bf16x8 aF[2][4];
#pragma unroll
            for (int c = 0; c < 2; ++c)
#pragma unroll
                for (int m = 0; m < 4; ++m) {
                    const int row = wr * 128 + mh * 64 + m * 16 + fr;
                    aF[c][m] = *(const bf16x8*)(la + row * 128 + ((c * 64 + g4 * 16) ^ mskK));
                }
            __builtin_amdgcn_s_setprio(1);
#pragma unroll
            for (int c = 0; c < 2; ++c)
#pragma unroll
                for (int n = 0; n < 4; ++n)
#pragma unroll
                    for (int m = 0; m < 4; ++m)
                        acc[mh * 4 + m][n] =
                            __builtin_amdgcn_mfma_f32_16x16x32_bf16(aF[c][m], bF[c][n], acc[mh * 4 + m][n], 0, 0, 0);
            __builtin_amdgcn_s_setprio(0);
        }

        __builtin_amdgcn_sched_barrier(0);
        asm volatile("s_barrier" ::: "memory");
        if (t + 2 < 16) stage(t & 1, t + 2);
    }

    const int cr = g4 * 4;
    const int cc = fr;
    if constexpr (OUT_MODE == 2) {
        const int b  = (int)(row0 >> 11);
        const int tb = ((int)row0 & 2047) + wr * 128 + cr;
#pragma unroll
        for (int m = 0; m < 8; ++m) {
#pragma unroll
            for (int n = 0; n < 4; ++n) {
                int col = col0 + wc * 64 + n * 16 + cc;
                float bv = bias[col];
                s16x4 o;
#pragma unroll
                for (int j = 0; j < 4; ++j) o[j] = (short)f2bf(acc[m][n][j] + bv);
                *(s16x4*)&((unsigned short*)out_)[((size_t)b * 1024 + col) * 2048 + tb + m * 16] = o;
            }
        }
    } else {
#pragma unroll
        for (int m = 0; m < 8; ++m) {
            long row = row0 + wr * 128 + m * 16 + cr;
#pragma unroll
            for (int n = 0; n < 4; ++n) {
                int col = col0 + wc * 64 + n * 16 + cc;
                float bv = bias[col];
#pragma unroll
                for (int j = 0; j < 4; ++j) {
                    float v = acc[m][n][j] + bv;
                    if constexpr (OUT_MODE == 1) ((float*)out_)[(row + j) * 1024 + col] = v;
                    else ((unsigned short*)out_)[(row + j) * 1024 + col] = f2bf(v);
                }
            }
        }
    }
}

template<int OUT_MODE>
__global__ __launch_bounds__(512, 2)
void gemm256(const unsigned short* __restrict__ A, const unsigned short* __restrict__ Bw,
             const float* __restrict__ bias, void* __restrict__ out_) {
    __shared__ __align__(16) unsigned short sA[2][16384];
    __shared__ __align__(16) unsigned short sB[2][16384];
    gemm_body<OUT_MODE>(A, Bw, bias, out_, blockIdx.x, gridDim.x, &sA[0][0], &sB[0][0]);
}

// two independent 1024x1024 GEMMs in one launch (grid = 32)
__global__ __launch_bounds__(512, 2)
void gemm_pair(const unsigned short* __restrict__ A0, const unsigned short* __restrict__ B0,
               const float* __restrict__ bias0, void* __restrict__ o0,
               const unsigned short* __restrict__ A1, const unsigned short* __restrict__ B1,
               const float* __restrict__ bias1, void* __restrict__ o1) {
    __shared__ __align__(16) unsigned short sA[2][16384];
    __shared__ __align__(16) unsigned short sB[2][16384];
    if (blockIdx.x < 16)
        gemm_body<0>(A0, B0, bias0, o0, blockIdx.x, 16, &sA[0][0], &sB[0][0]);
    else
        gemm_body<0>(A1, B1, bias1, o1, blockIdx.x - 16, 16, &sA[0][0], &sB[0][0]);
}

// ---------------------------------------------------------------------------
// prep_everything: ALL preprocessing in ONE launch. grid = 21770, block 256.
// q-transpose tile is 128t x 64d: each qt d-row written as 256B contiguous
// (round-13 counter: write-side limited at 1.2 TB/s with 128B chunks).
//  [0, 4096)      : qt[b][d][t] = bf16(queries[b][t][d])  (128x64 tiles)
//  [4096, 20480)  : ab = bf16(keys)                        (straight cast)
//  [20480, 21248) : Wv/Wq/Wk transpose-cast -> wvT/wqT/wkT (768 blocks)
//  [21248, 21504) : Wo cast -> wo                          (256 blocks)
//  [21504, 21513) : zero G (32800 f32)
//  21513          : zero zb1024
//  [21514, 21770) : b2[n] = Wo[n,:]·bv + bo[n]             (256 blocks)
// ---------------------------------------------------------------------------
__global__ __launch_bounds__(256)
void prep_everything(const float* __restrict__ queries, const float* __restrict__ keys,
                     const float* __restrict__ Wq, const float* __restrict__ Wk,
                     const float* __restrict__ Wv, const float* __restrict__ Wo,
                     const float* __restrict__ bv, const float* __restrict__ bo,
                     unsigned short* __restrict__ qt, unsigned short* __restrict__ ab,
                     unsigned short* __restrict__ wo, unsigned short* __restrict__ wvT,
                     unsigned short* __restrict__ wqT, unsigned short* __restrict__ wkT,
                     float* __restrict__ G, float* __restrict__ zb, float* __restrict__ b2) {
    __shared__ float tsm[128][65];
    const int bx  = blockIdx.x;
    const int tid = threadIdx.x;

    if (bx < 4096) {
        // qt[b][d0+dl][t0+tl] = bf16(queries[b][t0+tl][d0+dl]); tsm[t][d]
        const int b   = bx >> 8;            // 256 blocks/batch
        const int rem = bx & 255;
        const int t0  = (rem & 15) * 128;   // 16 t-tiles
        const int d0  = (rem >> 4) * 64;    // 16 d-tiles
        const int tx = tid & 63, ty = tid >> 6;
        const float* s = queries + ((size_t)b * 2048 + t0) * 1024 + d0;
        for (int r = ty; r < 128; r += 4)
            tsm[r][tx] = s[(size_t)r * 1024 + tx];
        __syncthreads();
        unsigned short* d = qt + ((size_t)b * 1024 + d0) * 2048 + t0;
        const int seg = tid & 15, rbase = tid >> 4;   // 16 t-segs x 16 d-rows
#pragma unroll
        for (int rr = 0; rr < 4; ++rr) {
            const int dl = rbase + rr * 16;
            bf16x8 o;
#pragma unroll
            for (int j = 0; j < 8; ++j) o[j] = (short)f2bf(tsm[seg * 8 + j][dl]);
            *(bf16x8*)(d + (size_t)dl * 2048 + seg * 8) = o;
        }
    } else if (bx < 20480) {
        const size_t i = ((size_t)(bx - 4096) * 256 + tid) * 8;
        f32x4 v0 = *(const f32x4*)(keys + i);
        f32x4 v1 = *(const f32x4*)(keys + i + 4);
        bf16x8 o;
#pragma unroll
        for (int j = 0; j < 4; ++j) o[j] = (short)f2bf(v0[j]);
#pragma unroll
        for (int j = 0; j < 4; ++j) o[4 + j] = (short)f2bf(v1[j]);
        *(bf16x8*)(ab + i) = o;
    } else if (bx < 21248) {
        // dst[b0+rl][by+cc] = bf16(src[by+cc][b0+rl]); tsm[srcrow][srccol]
        const int wx = bx - 20480;
        const float* src = (wx < 256) ? Wv : (wx < 512) ? Wq : Wk;
        unsigned short* dst = (wx < 256) ? wvT : (wx < 512) ? wqT : wkT;
        const int t  = wx & 255;
        const int b0 = (t & 15) * 64;
        const int by = (t >> 4) * 64;
        const int tx = tid & 63, ty = tid >> 6;
        for (int r = ty; r < 64; r += 4)
            tsm[r][tx] = src[(size_t)(by + r) * 1024 + b0 + tx];
        __syncthreads();
        const int seg = tid & 7, rbase = tid >> 3;
#pragma unroll
        for (int rr = 0; rr < 2; ++rr) {
            const int rl = rbase + rr * 32;
            bf16x8 o;
#pragma unroll
            for (int j = 0; j < 8; ++j) o[j] = (short)f2bf(tsm[seg * 8 + j][rl]);
            *(bf16x8*)(dst + (size_t)(b0 + rl) * 1024 + by + seg * 8) = o;
        }
    } else if (bx < 21504) {
        const int base = (bx - 21248) * 4096 + tid * 4;
#pragma unroll
        for (int r = 0; r < 4; ++r) {
            const int i = base + r * 1024;
            f32x4 v = *(const f32x4*)(Wo + i);
            s16x4 o;
#pragma unroll
            for (int j = 0; j < 4; ++j) o[j] = (short)f2bf(v[j]);
            *(s16x4*)(wo + i) = o;
        }
    } else if (bx < 21513) {
        const int base = (bx - 21504) * 4096;
#pragma unroll
        for (int r = 0; r < 16; ++r) {
            const int i = base + r * 256 + tid;
            if (i < 32800) G[i] = 0.0f;
        }
    } else if (bx == 21513) {
        *(f32x4*)(zb + tid * 4) = (f32x4){0.f, 0.f, 0.f, 0.f};
    } else {
        const int n = (bx - 21514) * 4 + (tid >> 6);
        const int lane = tid & 63;
        float s = 0.f;
        for (int k = lane; k < 1024; k += 64) s += Wo[(size_t)n * 1024 + k] * bv[k];
#pragma unroll
        for (int off = 32; off > 0; off >>= 1) s += __shfl_xor(s, off, 64);
        if (lane == 0) b2[n] = s + bo[n];
    }
}

// ---------------------------------------------------------------------------
// 8-point DFT (negative exponent), in place on xr/xi[8].
// ---------------------------------------------------------------------------
__device__ __forceinline__ void dft8(float* xr, float* xi) {
    const float c8 = 0.70710678118654752440f;
    float es0r = xr[0] + xr[4], es0i = xi[0] + xi[4];
    float es1r = xr[0] - xr[4], es1i = xi[0] - xi[4];
    float es2r = xr[2] + xr[6], es2i = xi[2] + xi[6];
    float es3r = xr[2] - xr[6], es3i = xi[2] - xi[6];
    float E0r = es0r + es2r, E0i = es0i + es2i;
    float E2r = es0r - es2r, E2i = es0i - es2i;
    float E1r = es1r + es3i, E1i = es1i - es3r;
    float E3r = es1r - es3i, E3i = es1i + es3r;
    float os0r = xr[1] + xr[5], os0i = xi[1] + xi[5];
    float os1r = xr[1] - xr[5], os1i = xi[1] - xi[5];
    float os2r = xr[3] + xr[7], os2i = xi[3] + xi[7];
    float os3r = xr[3] - xr[7], os3i = xi[3] - xi[7];
    float O0r = os0r + os2r, O0i = os0i + os2i;
    float O2r = os0r - os2r, O2i = os0i - os2i;
    float O1r = os1r + os3i, O1i = os1i - os3r;
    float O3r = os1r - os3i, O3i = os1i + os3r;
    float p1 = c8 * (O1r + O1i), q1 = c8 * (O1i - O1r);
    float p3 = c8 * (O3r + O3i), q3 = c8 * (O3i - O3r);
    xr[0] = E0r + O0r; xi[0] = E0i + O0i;
    xr[4] = E0r - O0r; xi[4] = E0i - O0i;
    xr[1] = E1r + p1;  xi[1] = E1i + q1;
    xr[5] = E1r - p1;  xi[5] = E1i - q1;
    xr[2] = E2r + O2i; xi[2] = E2i - O2r;
    xr[6] = E2r - O2i; xi[6] = E2i + O2r;
    xr[3] = E3r + q3;  xi[3] = E3i - p3;
    xr[7] = E3r - q3;  xi[7] = E3i + p3;
}

__device__ __forceinline__ int padc(int p) { return p + (p >> 5); }

// apply W^{k} chain (base wr_,wi_) to both streams a and b
#define TWIDDLE2(wr_, wi_)                                                    \
    {                                                                         \
        float cr_ = (wr_), ci_ = (wi_);                                       \
        _Pragma("unroll")                                                     \
        for (int k = 1; k < 8; ++k) {                                         \
            float t0 = ar[k] * cr_ - ai[k] * ci_;                             \
            float t1 = ar[k] * ci_ + ai[k] * cr_;                             \
            ar[k] = t0; ai[k] = t1;                                           \
            float t2 = br[k] * cr_ - bi[k] * ci_;                             \
            float t3 = br[k] * ci_ + bi[k] * cr_;                             \
            br[k] = t2; bi[k] = t3;                                           \
            if (k < 7) {                                                      \
                float nr = cr_ * (wr_) - ci_ * (wi_);                         \
                float ni = cr_ * (wi_) + ci_ * (wr_);                         \
                cr_ = nr; ci_ = ni;                                           \
            }                                                                 \
        }                                                                     \
    }

// ---------------------------------------------------------------------------
// fft_corr (round-12 verified: structural floor at ~116us for this
// decomposition). Dual-column batching, register accumulators, float2+padc,
// 4 barriers per iteration (R2->R3 and R3->R4 are intra-wave).
// grid = 2048 (16 b x 128 chunks), block = 256.
// ---------------------------------------------------------------------------
__global__ __launch_bounds__(256)
void fft_corr(const unsigned short* __restrict__ qt, const unsigned short* __restrict__ kt,
              float* __restrict__ G) {
    __shared__ float2 za[2112];
    __shared__ float2 zb[2112];
    float* zfr0 = (float*)za; float* zfi0 = zfr0 + 2112;
    float* zfr1 = (float*)zb; float* zfi1 = zfr1 + 2112;
    const int tid = threadIdx.x;
    const int b = blockIdx.x >> 7;
    const int chunk = blockIdx.x & 127;

    const float N2PI = -6.28318530717958647692f;
    float w1r, w1i, w2r, w2i, w3r, w3i;
    {
        float s, c;
        __sincosf(N2PI * (float)tid * (1.0f / 2048.0f), &s, &c); w1r = c; w1i = s;
        __sincosf(N2PI * (float)(tid & 31) * (1.0f / 256.0f), &s, &c); w2r = c; w2i = s;
        __sincosf(N2PI * (float)(tid & 3) * (1.0f / 32.0f),  &s, &c); w3r = c; w3i = s;
    }

    float aR0 = 0.f, aI0 = 0.f, aR1 = 0.f, aI1 = 0.f;
    float aR2 = 0.f, aI2 = 0.f, aR3 = 0.f, aI3 = 0.f, aR4 = 0.f;

    const int beta = tid >> 5, s2 = tid & 31;
    const int gam  = tid >> 2, u3 = tid & 3;

    for (int it = 0; it < 4; ++it) {
        const int d0 = chunk * 8 + it * 2;
        const unsigned short* q0 = qt + ((size_t)b * 1024 + d0) * 2048;
        const unsigned short* k0 = kt + ((size_t)b * 1024 + d0) * 2048;
        const unsigned short* q1 = q0 + 2048;
        const unsigned short* k1 = k0 + 2048;

        float ar[8], ai[8], br[8], bi[8];
#pragma unroll
        for (int k = 0; k < 8; ++k) {
            ar[k] = bf2f(q0[tid + 256 * k]); ai[k] = bf2f(k0[tid + 256 * k]);
            br[k] = bf2f(q1[tid + 256 * k]); bi[k] = bf2f(k1[tid + 256 * k]);
        }
        dft8(ar, ai); dft8(br, bi);
        TWIDDLE2(w1r, w1i)
#pragma unroll
        for (int k = 0; k < 8; ++k) {
            const int p = padc(256 * k + tid);
            za[p] = make_float2(ar[k], ai[k]);
            zb[p] = make_float2(br[k], bi[k]);
        }
        __syncthreads();   // R1 writers cross-wave: barrier REQUIRED

#pragma unroll
        for (int k = 0; k < 8; ++k) {
            const int p = padc(256 * beta + 32 * k + s2);
            float2 va = za[p]; ar[k] = va.x; ai[k] = va.y;
            float2 vb = zb[p]; br[k] = vb.x; bi[k] = vb.y;
        }
        dft8(ar, ai); dft8(br, bi);
        TWIDDLE2(w2r, w2i)
#pragma unroll
        for (int k = 0; k < 8; ++k) {
            const int p = padc(256 * beta + 32 * k + s2);
            za[p] = make_float2(ar[k], ai[k]);
            zb[p] = make_float2(br[k], bi[k]);
        }
        // NO barrier: R3's reads come from its own wave's R2 writes.

#pragma unroll
        for (int k = 0; k < 8; ++k) {
            const int p = padc(32 * gam + 4 * k + u3);
            float2 va = za[p]; ar[k] = va.x; ai[k] = va.y;
            float2 vb = zb[p]; br[k] = vb.x; bi[k] = vb.y;
        }
        dft8(ar, ai); dft8(br, bi);
        TWIDDLE2(w3r, w3i)
#pragma unroll
        for (int k = 0; k < 8; ++k) {
            const int p = padc(32 * gam + 4 * k + u3);
            za[p] = make_float2(ar[k], ai[k]);
            zb[p] = make_float2(br[k], bi[k]);
        }
        // NO barrier: R4 reads its own 4-lane group's R3 writes.

#pragma unroll
        for (int k = 0; k < 8; ++k) {
            const int p = padc(8 * tid + k);
            float2 va = za[p]; ar[k] = va.x; ai[k] = va.y;
            float2 vb = zb[p]; br[k] = vb.x; bi[k] = vb.y;
        }
        __syncthreads();   // anti-dep: scatter overwrites other waves' R4 reads

#pragma unroll
        for (int blk = 0; blk < 2; ++blk) {
            const int o = 4 * blk;
            {
                float s0r = ar[o] + ar[o + 2], s0i = ai[o] + ai[o + 2];
                float s1r = ar[o] - ar[o + 2], s1i = ai[o] - ai[o + 2];
                float s2r = ar[o + 1] + ar[o + 3], s2i = ai[o + 1] + ai[o + 3];
                float s3r = ar[o + 1] - ar[o + 3], s3i = ai[o + 1] - ai[o + 3];
                ar[o + 0] = s0r + s2r; ai[o + 0] = s0i + s2i;
                ar[o + 2] = s0r - s2r; ai[o + 2] = s0i - s2i;
                ar[o + 1] = s1r + s3i; ai[o + 1] = s1i - s3r;
                ar[o + 3] = s1r - s3i; ai[o + 3] = s1i + s3r;
            }
            {
                float s0r = br[o] + br[o + 2], s0i = bi[o] + bi[o + 2];
                float s1r = br[o] - br[o + 2], s1i = bi[o] - bi[o + 2];
                float s2r = br[o + 1] + br[o + 3], s2i = bi[o + 1] + bi[o + 3];
                float s3r = br[o + 1] - br[o + 3], s3i = bi[o + 1] - bi[o + 3];
                br[o + 0] = s0r + s2r; bi[o + 0] = s0i + s2i;
                br[o + 2] = s0r - s2r; bi[o + 2] = s0i - s2i;
                br[o + 1] = s1r + s3i; bi[o + 1] = s1i - s3r;
                br[o + 3] = s1r - s3i; bi[o + 3] = s1i + s3r;
            }
        }
        {
            const int k1d = tid >> 5;
            const int k2d = (tid >> 2) & 7;
            const int fb = k1d + 8 * k2d;
#pragma unroll
            for (int blk = 0; blk < 2; ++blk) {
                const int k3d = (2 * (tid & 3) + blk) & 7;
#pragma unroll
                for (int k4 = 0; k4 < 4; ++k4) {
                    const int f = fb + 64 * k3d + 512 * k4;
                    const int pf = padc(f);
                    zfr0[pf] = ar[4 * blk + k4]; zfi0[pf] = ai[4 * blk + k4];
                    zfr1[pf] = br[4 * blk + k4]; zfi1[pf] = bi[4 * blk + k4];
                }
            }
        }
        __syncthreads();   // scatter writers cross-wave before Hermitian reads

        // Hermitian split + accumulate (registers)
#pragma unroll
        for (int k = 0; k < 4; ++k) {
            const int f = tid + 256 * k;
            const int f2 = (2048 - f) & 2047;
            const int pf = padc(f), pf2 = padc(f2);
            float Zr = zfr0[pf],  Zi = zfi0[pf];
            float Yr = zfr0[pf2], Yi = -zfi0[pf2];
            float Qr = 0.5f * (Zr + Yr), Qi = 0.5f * (Zi + Yi);
            float Kr = 0.5f * (Zi - Yi), Ki = -0.5f * (Zr - Yr);
            float dR = Qr * Kr + Qi * Ki;
            float dI = Qi * Kr - Qr * Ki;
            Zr = zfr1[pf];  Zi = zfi1[pf];
            Yr = zfr1[pf2]; Yi = -zfi1[pf2];
            Qr = 0.5f * (Zr + Yr); Qi = 0.5f * (Zi + Yi);
            Kr = 0.5f * (Zi - Yi); Ki = -0.5f * (Zr - Yr);
            dR += Qr * Kr + Qi * Ki;
            dI += Qi * Kr - Qr * Ki;
            if      (k == 0) { aR0 += dR; aI0 += dI; }
            else if (k == 1) { aR1 += dR; aI1 += dI; }
            else if (k == 2) { aR2 += dR; aI2 += dI; }
            else             { aR3 += dR; aI3 += dI; }
        }
        if (tid == 0) {   // f = 1024: Q = Re(Z), K = Im(Z), P imag = 0
            const int pf = padc(1024);
            aR4 += zfr0[pf] * zfi0[pf] + zfr1[pf] * zfi1[pf];
        }
        __syncthreads();   // anti-dep: next iteration's R1 writes
    }

    atomicAdd(&G[((size_t)b * 1025 + tid +   0) * 2 + 0], aR0);
    atomicAdd(&G[((size_t)b * 1025 + tid +   0) * 2 + 1], aI0);
    atomicAdd(&G[((size_t)b * 1025 + tid + 256) * 2 + 0], aR1);
    atomicAdd(&G[((size_t)b * 1025 + tid + 256) * 2 + 1], aI1);
    atomicAdd(&G[((size_t)b * 1025 + tid + 512) * 2 + 0], aR2);
    atomicAdd(&G[((size_t)b * 1025 + tid + 512) * 2 + 1], aI2);
    atomicAdd(&G[((size_t)b * 1025 + tid + 768) * 2 + 0], aR3);
    atomicAdd(&G[((size_t)b * 1025 + tid + 768) * 2 + 1], aI3);
    if (tid == 0)
        atomicAdd(&G[((size_t)b * 1025 + 1024) * 2 + 0], aR4);
}

// ---------------------------------------------------------------------------
// In-LDS radix-2 DIT FFT, N=2048 (only used by irfft_mean: 16 blocks, cheap).
// ---------------------------------------------------------------------------
__device__ __forceinline__ void fft2048(float* zr, float* zi,
                                        const float* twr, const float* twi, int tid) {
    for (int t = tid; t < 2048; t += 256) {
        int j = __brev((unsigned)t) >> 21;
        if (j > t) {
            float a = zr[t]; zr[t] = zr[j]; zr[j] = a;
            float c = zi[t]; zi[t] = zi[j]; zi[j] = c;
        }
    }
    __syncthreads();
    for (int s = 0; s < 11; ++s) {
        const int m = 1 << s;
        for (int i = tid; i < 1024; i += 256) {
            const int pos = i & (m - 1);
            const int i1  = ((i >> s) << (s + 1)) + pos;
            const int i2  = i1 + m;
            const int tw  = pos << (10 - s);
            float wr = twr[tw], wi = twi[tw];
            float xr = zr[i2], xi = zi[i2];
            float tr = wr * xr - wi * xi;
            float ti = wr * xi + wi * xr;
            float ur = zr[i1], ui = zi[i1];
            zr[i2] = ur - tr; zi[i2] = ui - ti;
            zr[i1] = ur + tr; zi[i1] = ui + ti;
        }
        __syncthreads();
    }
}

__device__ __forceinline__ void init_twiddle(float* twr, float* twi, int tid) {
    for (int j = tid; j < 1024; j += 256) {
        float ang = -6.28318530717958647692f * (float)j * (1.0f / 2048.0f);
        twr[j] = cosf(ang);
        twi[j] = sinf(ang);
    }
}

// ---------------------------------------------------------------------------
// Per-batch irfft of G -> mean_value[b][t], scale 1/(2048*1024). grid = 16.
// ---------------------------------------------------------------------------
__global__ __launch_bounds__(256)
void irfft_mean(const float* __restrict__ G, float* __restrict__ mv) {
    __shared__ float zr[2048], zi[2048];
    __shared__ float twr[1024], twi[1024];
    const int tid = threadIdx.x;
    const int b = blockIdx.x;
    init_twiddle(twr, twi, tid);
    for (int f = tid; f < 2048; f += 256) {
        int g = (f <= 1024) ? f : 2048 - f;
        float gr = G[((size_t)b * 1025 + g) * 2 + 0];
        float gi = G[((size_t)b * 1025 + g) * 2 + 1];
        zr[f] = gr;
        zi[f] = (f <= 1024) ? -gi : gi;
    }
    __syncthreads();
    fft2048(zr, zi, twr, twi, tid);
    const float sc = 1.0f / (2048.0f * 1024.0f);
    for (int t = tid; t < 2048; t += 256) mv[b * 2048 + t] = zr[t] * sc;
}

// ---------------------------------------------------------------------------
// Top-7 over batch-mean + per-batch softmax (parallel argmax).
// ---------------------------------------------------------------------------
__global__ __launch_bounds__(256)
void topk_softmax(const float* __restrict__ mv, int* __restrict__ idx_out,
                  float* __restrict__ w_out) {
    __shared__ float cm[2048];
    __shared__ float wv4[4];
    __shared__ int   wi4[4];
    __shared__ int   sel[7];
    const int tid  = threadIdx.x;
    const int lane = tid & 63;
    const int wvid = tid >> 6;

    for (int t = tid; t < 2048; t += 256) {
        float s = 0.f;
        for (int b = 0; b < 16; ++b) s += mv[b * 2048 + t];
        cm[t] = s * (1.0f / 16.0f);
    }
    __syncthreads();

    for (int it = 0; it < 7; ++it) {
        float best = -3.4e38f; int bi = 1 << 30;
#pragma unroll
        for (int q = 0; q < 8; ++q) {
            const int t = tid + q * 256;
            float v = cm[t];
            if (v > best || (v == best && t < bi)) { best = v; bi = t; }
        }
#pragma unroll
        for (int off = 32; off > 0; off >>= 1) {
            float ov = __shfl_xor(best, off, 64);
            int   oi = __shfl_xor(bi,   off, 64);
            if (ov > best || (ov == best && oi < bi)) { best = ov; bi = oi; }
        }
        if (lane == 0) { wv4[wvid] = best; wi4[wvid] = bi; }
        __syncthreads();
        if (tid == 0) {
            float bb = wv4[0]; int bj = wi4[0];
#pragma unroll
            for (int u = 1; u < 4; ++u)
                if (wv4[u] > bb || (wv4[u] == bb && wi4[u] < bj)) { bb = wv4[u]; bj = wi4[u]; }
            sel[it] = bj;
            idx_out[it] = bj;
            cm[bj] = -3.4e38f;
        }
        __syncthreads();
    }

    if (tid < 16) {
        const int b = tid;
        float wv[7]; float mx = -3.4e38f;
#pragma unroll
        for (int i = 0; i < 7; ++i) { wv[i] = mv[b * 2048 + sel[i]]; mx = fmaxf(mx, wv[i]); }
        float s = 0.f;
#pragma unroll
        for (int i = 0; i < 7; ++i) { wv[i] = expf(wv[i] - mx); s += wv[i]; }
        float inv = 1.0f / s;
#pragma unroll
        for (int i = 0; i < 7; ++i) w_out[b * 7 + i] = wv[i] * inv;
    }
}

// ---------------------------------------------------------------------------
// agg[b,t,d] = bf16( sum_i w[b,i] * values[b,(t+idx[i])%2048,d] )  (fp32 in)
// ---------------------------------------------------------------------------
__global__ __launch_bounds__(256)
void agg_kernel(const float* __restrict__ vsrc, const int* __restrict__ idx,
                const float* __restrict__ w, unsigned short* __restrict__ agg) {
    const int b  = blockIdx.y;
    const int t  = blockIdx.x * 2 + (threadIdx.x >> 7);
    const int d8 = (threadIdx.x & 127) * 8;
    float av[8] = {0.f, 0.f, 0.f, 0.f, 0.f, 0.f, 0.f, 0.f};
#pragma unroll
    for (int i = 0; i < 7; ++i) {
        const int srow = (t + idx[i]) & 2047;
        const float wi = w[b * 7 + i];
        const float* src = vsrc + ((size_t)b * 2048 + srow) * 1024 + d8;
        f32x4 v0 = *(const f32x4*)src;
        f32x4 v1 = *(const f32x4*)(src + 4);
#pragma unroll
        for (int j = 0; j < 4; ++j) av[j] += wi * v0[j];
#pragma unroll
        for (int j = 0; j < 4; ++j) av[4 + j] += wi * v1[j];
    }
    bf16x8 o;
#pragma unroll
    for (int j = 0; j < 8; ++j) o[j] = (short)f2bf(av[j]);
    *(bf16x8*)&agg[((size_t)b * 2048 + t) * 1024 + d8] = o;
}

// ---------------------------------------------------------------------------
extern "C" void kernel_launch(void* const* d_in, const int* in_sizes, int n_in,
                              void* d_out, int out_size, void* d_ws, size_t ws_size,
                              hipStream_t stream) {
    const float* queries = (const float*)d_in[0];
    const float* keys    = (const float*)d_in[1];
    const float* values  = (const float*)d_in[2];
    const float* Wq = (const float*)d_in[3];
    const float* Wk = (const float*)d_in[5];
    const float* Wv = (const float*)d_in[7];  const float* bv = (const float*)d_in[8];
    const float* Wo = (const float*)d_in[9];  const float* bo = (const float*)d_in[10];
    float* out = (float*)d_out;

    char* ws = (char*)d_ws;
    constexpr size_t SZP = (size_t)32768 * 1024 * 2;           // 64 MB (bf16 B*L*D)
    unsigned short* agg = (unsigned short*)(ws);               // agg output [b][t][d]
    unsigned short* kt  = (unsigned short*)(ws + SZP);         // k~^T [b][d][t]
    unsigned short* qt  = (unsigned short*)(ws + 2 * SZP);     // q^T  [b][d][t]
    unsigned short* ab  = (unsigned short*)(ws + 3 * SZP);     // staging (64MB)
    unsigned short* W2  = (unsigned short*)(ws + 4 * SZP);     // bf16 Wo@Wv   [N][K]
    unsigned short* M   = W2 + 1048576;                        // bf16 Wq^T@Wk [N][K]
    unsigned short* wtmp = M + 1048576;                        // 4 x 1M bf16 weight temps
    unsigned short* wo  = wtmp;
    unsigned short* wvT = wtmp + 1048576;
    unsigned short* wqT = wtmp + 2097152;
    unsigned short* wkT = wtmp + 3145728;
    char* tail = ws + 4 * SZP + 4194304 + 8388608;
    float* zb1024 = (float*)(tail);                            // 4KB zero bias
    float* b2     = (float*)(tail + 4096);
    float* G      = (float*)(tail + 8192);                     // 16*1025*2 f32
    float* mv     = (float*)(tail + 8192 + 131328);
    int*   idx    = (int*)  (tail + 8192 + 131328 + 131072);
    float* wsm    = (float*)(tail + 8192 + 131328 + 131072 + 64);

    // 1) ALL prep in one launch (inputs + weights + zeros + b2)
    prep_everything<<<21770, 256, 0, stream>>>(queries, keys, Wq, Wk, Wv, Wo, bv, bo,
                                               qt, ab, wo, wvT, wqT, wkT,
                                               G, zb1024, b2);
    // 2) W2 = Wo@Wv and M = Wq^T@Wk in one launch
    gemm_pair<<<32, 512, 0, stream>>>(wo, wvT, zb1024, W2,
                                      wqT, wkT, zb1024, M);
    // 3) k~ = k @ M^T (transposed out)
    gemm256<2><<<512, 512, 0, stream>>>(ab, M, zb1024, kt);

    // 4) correlation -> top-k -> aggregation -> fused output GEMM
    fft_corr<<<2048, 256, 0, stream>>>(qt, kt, G);
    irfft_mean<<<16, 256, 0, stream>>>(G, mv);
    topk_softmax<<<1, 256, 0, stream>>>(mv, idx, wsm);
    agg_kernel<<<dim3(1024, 16), 256, 0, stream>>>(values, idx, wsm, agg);
    gemm256<1><<<512, 512, 0, stream>>>(agg, W2, b2, out);
}